// Round 1
// baseline (87.551 us; speedup 1.0000x reference)
//
#include <hip/hip_runtime.h>
#include <hip/hip_bf16.h>

#define TOKENS   16384      // B*N = 4*4096
#define DIM      2048
#define NEXP     8
#define NBATCH   4
#define TOK_PER_B 4096      // N
#define KTOP     2
#define ALPHA    0.1f

// ws layout: [0..31]  score sums per (b,e)
//            [32..63] top-k counts per (b,e)  (as float)

__global__ __launch_bounds__(256)
void gate_kernel(const float* __restrict__ x, const float* __restrict__ W,
                 float* __restrict__ out, float* __restrict__ ws)
{
    __shared__ float Wl[NEXP * DIM];          // 64 KiB
    __shared__ float s_sum[NBATCH * NEXP];
    __shared__ float s_cnt[NBATCH * NEXP];

    const int tid = threadIdx.x;
    if (tid < NBATCH * NEXP) { s_sum[tid] = 0.f; s_cnt[tid] = 0.f; }

    // Cooperative W load: 16384 floats = 4096 float4, 256 threads -> 16 each
    {
        const float4* W4  = (const float4*)W;
        float4*       Wl4 = (float4*)Wl;
        #pragma unroll
        for (int i = 0; i < (NEXP * DIM / 4) / 256; ++i)
            Wl4[tid + i * 256] = W4[tid + i * 256];
    }
    __syncthreads();

    const int wave  = tid >> 6;
    const int lane  = tid & 63;
    const int gwave = blockIdx.x * 4 + wave;
    const int nw    = gridDim.x * 4;

    for (int t = gwave; t < TOKENS; t += nw) {
        const float4* xp = (const float4*)(x + (size_t)t * DIM);

        // Coalesced: instruction i reads a contiguous 1 KiB segment.
        float4 xv[8];
        #pragma unroll
        for (int i = 0; i < 8; ++i) xv[i] = xp[lane + i * 64];

        float logit[NEXP];
        #pragma unroll
        for (int e = 0; e < NEXP; ++e) {
            const float4* wp = (const float4*)(Wl + e * DIM);
            float acc = 0.f;
            #pragma unroll
            for (int i = 0; i < 8; ++i) {
                float4 wv = wp[lane + i * 64];   // consecutive-lane ds_read_b128: conflict-free
                acc += xv[i].x * wv.x + xv[i].y * wv.y
                     + xv[i].z * wv.z + xv[i].w * wv.w;
            }
            logit[e] = acc;
        }

        // Butterfly reduce over 64 lanes; all lanes end with full sums.
        #pragma unroll
        for (int e = 0; e < NEXP; ++e) {
            float v = logit[e];
            #pragma unroll
            for (int off = 32; off; off >>= 1) v += __shfl_xor(v, off, 64);
            logit[e] = v;
        }

        // Softmax over 8 experts (redundant per-lane; cheap).
        float m = logit[0];
        #pragma unroll
        for (int e = 1; e < NEXP; ++e) m = fmaxf(m, logit[e]);
        float p[NEXP], s = 0.f;
        #pragma unroll
        for (int e = 0; e < NEXP; ++e) { p[e] = expf(logit[e] - m); s += p[e]; }
        const float inv = 1.f / s;
        #pragma unroll
        for (int e = 0; e < NEXP; ++e) p[e] *= inv;

        // Top-2, jax tie-break (lowest index wins on ties -> strict >).
        int i0 = 0; float v0 = p[0];
        #pragma unroll
        for (int e = 1; e < NEXP; ++e) if (p[e] > v0) { v0 = p[e]; i0 = e; }
        int i1 = -1; float v1 = -1.f;
        #pragma unroll
        for (int e = 0; e < NEXP; ++e) if (e != i0 && p[e] > v1) { v1 = p[e]; i1 = e; }

        const int b = t >> 12;   // t / 4096
        if (lane == 0) {
            out[(size_t)t * 2 + 0] = v0;
            out[(size_t)t * 2 + 1] = v1;
            out[(size_t)TOKENS * 2 + (size_t)t * 2 + 0] = (float)i0;
            out[(size_t)TOKENS * 2 + (size_t)t * 2 + 1] = (float)i1;
            atomicAdd(&s_cnt[b * NEXP + i0], 1.f);
            atomicAdd(&s_cnt[b * NEXP + i1], 1.f);
        }
        if (lane < NEXP) atomicAdd(&s_sum[b * NEXP + lane], p[lane]);
    }

    __syncthreads();
    if (tid < NBATCH * NEXP) {
        atomicAdd(&ws[tid],                 s_sum[tid]);
        atomicAdd(&ws[NBATCH * NEXP + tid], s_cnt[tid]);
    }
}

__global__ void finalize_kernel(const float* __restrict__ ws, float* __restrict__ out)
{
    if (threadIdx.x == 0 && blockIdx.x == 0) {
        float aux = 0.f;
        for (int b = 0; b < NBATCH; ++b) {
            float acc = 0.f;
            for (int e = 0; e < NEXP; ++e) {
                float pi = ws[b * NEXP + e] * (1.f / TOK_PER_B);
                float fi = ws[NBATCH * NEXP + b * NEXP + e]
                           * ((float)NEXP / ((float)KTOP * (float)TOK_PER_B));
                acc += fi * pi;
            }
            aux += acc;
        }
        out[(size_t)TOKENS * 4] = aux * (1.f / NBATCH) * ALPHA;  // out[65536]
    }
}

extern "C" void kernel_launch(void* const* d_in, const int* in_sizes, int n_in,
                              void* d_out, int out_size, void* d_ws, size_t ws_size,
                              hipStream_t stream) {
    const float* x = (const float*)d_in[0];
    const float* W = (const float*)d_in[1];
    float* out = (float*)d_out;
    float* ws  = (float*)d_ws;

    hipMemsetAsync(d_ws, 0, 2 * NBATCH * NEXP * sizeof(float), stream);

    dim3 grid(1024), block(256);
    gate_kernel<<<grid, block, 0, stream>>>(x, W, out, ws);
    finalize_kernel<<<1, 64, 0, stream>>>(ws, out);
}

// Round 2
// 48.344 us; speedup vs baseline: 1.8110x; 1.8110x over previous
//
#include <hip/hip_runtime.h>
#include <hip/hip_bf16.h>

#define TOKENS    16384      // B*N = 4*4096
#define DIM       2048
#define NEXP      8
#define NBATCH    4
#define TOK_PER_B 4096       // N
#define KTOP      2
#define ALPHA     0.1f

// ws layout: [0..31]  score sums per (b,e)
//            [32..63] top-k counts per (b,e)  (as float)

__device__ __forceinline__ float dot4(float4 a, float4 b) {
    return a.x * b.x + a.y * b.y + a.z * b.z + a.w * b.w;
}

__global__ __launch_bounds__(512, 4)
void gate_kernel(const float* __restrict__ x, const float* __restrict__ W,
                 float* __restrict__ out, float* __restrict__ ws)
{
    __shared__ float Wl[NEXP * DIM];          // 64 KiB
    __shared__ float s_sum[NBATCH * NEXP];
    __shared__ float s_cnt[NBATCH * NEXP];

    const int tid = threadIdx.x;
    if (tid < NBATCH * NEXP) { s_sum[tid] = 0.f; s_cnt[tid] = 0.f; }

    // Cooperative W load: 4096 float4 across 512 threads -> 8 each.
    {
        const float4* W4  = (const float4*)W;
        float4*       Wl4 = (float4*)Wl;
        #pragma unroll
        for (int i = 0; i < (NEXP * DIM / 4) / 512; ++i)
            Wl4[tid + i * 512] = W4[tid + i * 512];
    }
    __syncthreads();

    const int wave = tid >> 6;                 // 0..7
    const int lane = tid & 63;
    const int gw   = blockIdx.x * 8 + wave;    // 0..4095; owns tokens [gw*4, gw*4+4)

    #pragma unroll
    for (int it = 0; it < 2; ++it) {
        const int t0 = gw * 4 + it * 2;        // two tokens: t0, t0+1 (same batch)

        const float4* xp0 = (const float4*)(x + (size_t)t0 * DIM);
        const float4* xp1 = xp0 + DIM / 4;

        float4 a[8], b[8];
        #pragma unroll
        for (int i = 0; i < 8; ++i) {
            a[i] = xp0[lane + i * 64];         // each instr: contiguous 1 KiB segment
            b[i] = xp1[lane + i * 64];
        }

        float lg0[NEXP], lg1[NEXP];
        #pragma unroll
        for (int e = 0; e < NEXP; ++e) {
            const float4* wp = (const float4*)(Wl + e * DIM);
            float acc0 = 0.f, acc1 = 0.f;
            #pragma unroll
            for (int i = 0; i < 8; ++i) {
                float4 wv = wp[lane + i * 64]; // one ds_read_b128 feeds BOTH tokens
                acc0 += dot4(a[i], wv);
                acc1 += dot4(b[i], wv);
            }
            lg0[e] = acc0; lg1[e] = acc1;
        }

        // Butterfly reduce across 64 lanes (all lanes end with full sums).
        #pragma unroll
        for (int e = 0; e < NEXP; ++e) {
            float v0 = lg0[e], v1 = lg1[e];
            #pragma unroll
            for (int off = 32; off; off >>= 1) {
                v0 += __shfl_xor(v0, off, 64);
                v1 += __shfl_xor(v1, off, 64);
            }
            lg0[e] = v0; lg1[e] = v1;
        }

        const int bidx = t0 >> 12;             // batch index

        #pragma unroll
        for (int tk = 0; tk < 2; ++tk) {
            float* lg = tk ? lg1 : lg0;
            const int t = t0 + tk;

            // Softmax over 8 experts (redundant per-lane; cheap).
            float m = lg[0];
            #pragma unroll
            for (int e = 1; e < NEXP; ++e) m = fmaxf(m, lg[e]);
            float p[NEXP], s = 0.f;
            #pragma unroll
            for (int e = 0; e < NEXP; ++e) { p[e] = expf(lg[e] - m); s += p[e]; }
            const float inv = 1.f / s;
            #pragma unroll
            for (int e = 0; e < NEXP; ++e) p[e] *= inv;

            // Top-2, jax tie-break (lowest index wins -> strict >).
            int i0 = 0; float v0 = p[0];
            #pragma unroll
            for (int e = 1; e < NEXP; ++e) if (p[e] > v0) { v0 = p[e]; i0 = e; }
            int i1 = -1; float v1 = -1.f;
            #pragma unroll
            for (int e = 0; e < NEXP; ++e) if (e != i0 && p[e] > v1) { v1 = p[e]; i1 = e; }

            if (lane == 0) {
                out[(size_t)t * 2 + 0] = v0;
                out[(size_t)t * 2 + 1] = v1;
                out[(size_t)TOKENS * 2 + (size_t)t * 2 + 0] = (float)i0;
                out[(size_t)TOKENS * 2 + (size_t)t * 2 + 1] = (float)i1;
                atomicAdd(&s_cnt[bidx * NEXP + i0], 1.f);
                atomicAdd(&s_cnt[bidx * NEXP + i1], 1.f);
            }
            if (lane < NEXP) atomicAdd(&s_sum[bidx * NEXP + lane], p[lane]);
        }
    }

    __syncthreads();
    if (tid < NBATCH * NEXP) {
        atomicAdd(&ws[tid],                 s_sum[tid]);
        atomicAdd(&ws[NBATCH * NEXP + tid], s_cnt[tid]);
    }
}

__global__ void finalize_kernel(const float* __restrict__ ws, float* __restrict__ out)
{
    if (threadIdx.x == 0 && blockIdx.x == 0) {
        float aux = 0.f;
        for (int b = 0; b < NBATCH; ++b) {
            float acc = 0.f;
            for (int e = 0; e < NEXP; ++e) {
                float pi = ws[b * NEXP + e] * (1.f / TOK_PER_B);
                float fi = ws[NBATCH * NEXP + b * NEXP + e]
                           * ((float)NEXP / ((float)KTOP * (float)TOK_PER_B));
                acc += fi * pi;
            }
            aux += acc;
        }
        out[(size_t)TOKENS * 4] = aux * (1.f / NBATCH) * ALPHA;  // out[65536]
    }
}

extern "C" void kernel_launch(void* const* d_in, const int* in_sizes, int n_in,
                              void* d_out, int out_size, void* d_ws, size_t ws_size,
                              hipStream_t stream) {
    const float* x = (const float*)d_in[0];
    const float* W = (const float*)d_in[1];
    float* out = (float*)d_out;
    float* ws  = (float*)d_ws;

    hipMemsetAsync(d_ws, 0, 2 * NBATCH * NEXP * sizeof(float), stream);

    dim3 grid(512), block(512);
    gate_kernel<<<grid, block, 0, stream>>>(x, W, out, ws);
    finalize_kernel<<<1, 64, 0, stream>>>(ws, out);
}